// Round 1
// baseline (144.340 us; speedup 1.0000x reference)
//
#include <hip/hip_runtime.h>
#include <hip/hip_bf16.h>
#include <stdint.h>

// TarMAC ensemble attention, MI355X/gfx950.
// E=128 ensembles x NB=256 agents, DQ=DK=DV=256 (D=768), f32 in/out, bf16 MFMA compute.
//
// Pipeline: detect-mask-dtype -> prep Q/K bf16 -> prep V^T bf16 (tiled transpose)
//           -> audible bitmask -> fused attention (QK^T, masked softmax, PV).
// Workspace layout (needs ~51.4 MB):
//   Qb  @ 0        : 32768x256 bf16 (16 MiB)   q*(|s|+1), noise[:, :DQ]==0 so skipped
//   Kb  @ 16 MiB   : 32768x256 bf16
//   Vt  @ 32 MiB   : per-e transposed V, rows=d cols=k, bf16
//   aud @ 48 MiB   : 32768 x 8 u32 bit-rows (mask & dist<15)
//   flag@ 49 MiB   : mask dtype flag (1=int32, 0=byte)

#define EE   128
#define NBB  256
#define DDIM 768
#define NEGV (-1000000.0f)

typedef __attribute__((ext_vector_type(8))) short short8;   // 8 x bf16 (4 VGPRs)
typedef __attribute__((ext_vector_type(4))) float f32x4;    // MFMA accumulator

__device__ __forceinline__ unsigned short f2bf(float f){
  union { float f; unsigned u; } v; v.f = f;
  return (unsigned short)((v.u + 0x7FFFu + ((v.u >> 16) & 1u)) >> 16);  // RNE, finite inputs
}

// ---------- kernel 0: mask dtype probe ----------
// bool bytes (90% ones) read as u32 give values like 0x01010101 (>1) => flag 0.
// int32 0/1 values stay <=1 => flag 1.
__global__ void k_detect(const unsigned* __restrict__ mask, unsigned* __restrict__ flag){
  if(threadIdx.x == 0){
    unsigned ok = 1u;
    for(int i = 0; i < 64; ++i) if(mask[i] > 1u){ ok = 0u; break; }
    *flag = ok;
  }
}

// ---------- kernel 1: Q (scaled) and K -> bf16 ----------
__global__ void k_prep_qk(const float* __restrict__ qkv, const float* __restrict__ noise,
                          const float* __restrict__ sp,
                          unsigned short* __restrict__ Qb, unsigned short* __restrict__ Kb){
  const float scale = fabsf(sp[0]) + 1.0f;
  const int total = EE * NBB * 128;            // 4-wide chunks over cols [0,512)
  for(int idx = blockIdx.x * blockDim.x + threadIdx.x; idx < total; idx += gridDim.x * blockDim.x){
    const int n   = idx >> 7;
    const int col = (idx & 127) << 2;          // waves stay uniform across the 256 boundary
    f32x4 v = *(const f32x4*)(qkv + (size_t)n * DDIM + col);
    if(col < 256){                             // Q: noise slice is exactly zero -> skip read
      ushort4 o = make_ushort4(f2bf(v[0]*scale), f2bf(v[1]*scale),
                               f2bf(v[2]*scale), f2bf(v[3]*scale));
      *(ushort4*)(Qb + (size_t)n * 256 + col) = o;
    } else {
      f32x4 nz = *(const f32x4*)(noise + (size_t)n * DDIM + col);
      ushort4 o = make_ushort4(f2bf(v[0]+nz[0]), f2bf(v[1]+nz[1]),
                               f2bf(v[2]+nz[2]), f2bf(v[3]+nz[3]));
      *(ushort4*)(Kb + (size_t)n * 256 + (col - 256)) = o;
    }
  }
}

// ---------- kernel 2: V + noise -> transposed bf16 (Vt[e][d][k]) ----------
__global__ void k_prep_vt(const float* __restrict__ qkv, const float* __restrict__ noise,
                          unsigned short* __restrict__ Vt){
  __shared__ unsigned short tile[64 * 66];     // 64x64 tile, stride 66 to spread banks
  const int b = blockIdx.x;
  const int e = b >> 4, t4 = b & 15;
  const int k0 = (t4 >> 2) << 6, d0 = (t4 & 3) << 6;
  const int u = threadIdx.x & 15, r = threadIdx.x >> 4;
  #pragma unroll
  for(int i = 0; i < 4; ++i){
    const int kl = r + (i << 4);
    const size_t off = ((size_t)(e*NBB + k0 + kl)) * DDIM + 512 + d0 + (u << 2);
    f32x4 v  = *(const f32x4*)(qkv   + off);
    f32x4 nz = *(const f32x4*)(noise + off);
    const int base = kl * 66 + (u << 2);
    tile[base+0] = f2bf(v[0]+nz[0]); tile[base+1] = f2bf(v[1]+nz[1]);
    tile[base+2] = f2bf(v[2]+nz[2]); tile[base+3] = f2bf(v[3]+nz[3]);
  }
  __syncthreads();
  #pragma unroll
  for(int i = 0; i < 4; ++i){
    const int dl = r + (i << 4);
    unsigned short o0 = tile[(u*4+0)*66 + dl];
    unsigned short o1 = tile[(u*4+1)*66 + dl];
    unsigned short o2 = tile[(u*4+2)*66 + dl];
    unsigned short o3 = tile[(u*4+3)*66 + dl];
    *(ushort4*)(Vt + ((size_t)(e*NBB + d0 + dl)) * NBB + k0 + (u << 2)) =
        make_ushort4(o0, o1, o2, o3);
  }
}

// ---------- kernel 3: audible bitmask (mask & dist<15) ----------
__global__ void k_audible(const unsigned char* __restrict__ m8, const int* __restrict__ m32,
                          const float* __restrict__ pos, const unsigned* __restrict__ flag,
                          unsigned* __restrict__ aud){
  __shared__ float px[NBB], py[NBB];
  const int e = blockIdx.x, q = threadIdx.x;
  px[q] = pos[((size_t)(e*NBB + q)) * 2];
  py[q] = pos[((size_t)(e*NBB + q)) * 2 + 1];
  __syncthreads();
  const int isInt = (*flag != 0u);
  const float qx = px[q], qy = py[q];
  const size_t nrow = (size_t)(e*NBB + q) * NBB;
  for(int j = 0; j < 8; ++j){
    unsigned w = 0u;
    for(int kk = 0; kk < 32; ++kk){
      const int k = (j << 5) | kk;
      const int mk = isInt ? (m32[nrow + k] != 0) : (m8[nrow + k] != 0);
      const float dx = px[k] - qx, dy = py[k] - qy;
      // block fp-contract so sqrt boundary matches numpy exactly
      const float d2 = __fadd_rn(__fmul_rn(dx, dx), __fmul_rn(dy, dy));
      if(mk && (sqrtf(d2) < 15.0f)) w |= 1u << kk;
    }
    aud[(size_t)(e*NBB + q) * 8 + j] = w;
  }
}

// ---------- kernel 4: fused attention ----------
// Block = (e, q-half): 4 waves x 32 q-rows. 16x16x32 bf16 MFMA.
// LDS: [0,64K) K/Vt staging halves (swizzled), [64K,128K) per-wave P, [128K,+4K) audible.
__launch_bounds__(256, 1)
__global__ void k_attn(const unsigned short* __restrict__ Qb,
                       const unsigned short* __restrict__ Kb,
                       const unsigned short* __restrict__ Vt,
                       const unsigned* __restrict__ aud,
                       float* __restrict__ out){
  extern __shared__ unsigned char smem[];
  unsigned short* ldsKV = (unsigned short*)smem;
  unsigned short* ldsP  = (unsigned short*)(smem + 65536);
  unsigned*       audL  = (unsigned*)(smem + 131072);

  const int bid   = blockIdx.x;
  const int e     = ((bid & 7) << 4) + (bid >> 4);  // (e,qhalf) pair lands on one XCD
  const int qhalf = (bid >> 3) & 1;
  const int tid   = threadIdx.x;
  const int wave  = tid >> 6;
  const int lane  = tid & 63;
  const int g     = lane >> 4;
  const int u     = lane & 15;
  const int q0    = qhalf * 128 + wave * 32;
  const size_t ebase = (size_t)e * NBB;

  { // stage audible words for this block's 128 rows
    const unsigned* src = aud + (ebase + (size_t)qhalf * 128) * 8;
    #pragma unroll
    for(int i = 0; i < 4; ++i) audL[tid + i*256] = src[tid + i*256];
  }

  // Q A-fragments: Q[q0+mt*16+u][dk*32+g*8 .. +7]
  short8 qf[2][8];
  #pragma unroll
  for(int mt = 0; mt < 2; ++mt)
    #pragma unroll
    for(int dk = 0; dk < 8; ++dk)
      qf[mt][dk] = *(const short8*)(Qb + (ebase + q0 + mt*16 + u) * 256 + dk*32 + g*8);

  const f32x4 zero4 = {0.f, 0.f, 0.f, 0.f};
  f32x4 acc[2][16];
  #pragma unroll
  for(int mt = 0; mt < 2; ++mt)
    #pragma unroll
    for(int nt = 0; nt < 16; ++nt) acc[mt][nt] = zero4;

  // ---- S = Q K^T over two staged K halves ----
  #pragma unroll
  for(int kh = 0; kh < 2; ++kh){
    __syncthreads();
    const unsigned short* Ksrc = Kb + (ebase + (size_t)kh * 128) * 256;
    #pragma unroll
    for(int i = 0; i < 16; ++i){
      const int c = tid + i*256;
      const int row = c >> 5, col = (c & 31) * 8;
      short8 d = *(const short8*)(Ksrc + (size_t)row * 256 + col);
      *(short8*)(ldsKV + row*256 + (col ^ ((row & 7) << 3))) = d;   // XOR bank swizzle
    }
    __syncthreads();
    #pragma unroll
    for(int nth = 0; nth < 8; ++nth){
      const unsigned short* kr = ldsKV + (nth*16 + u) * 256;
      const int sw = (u & 7) << 3;
      #pragma unroll
      for(int dk = 0; dk < 8; ++dk){
        short8 kb = *(const short8*)(kr + ((dk*32 + g*8) ^ sw));
        acc[0][kh*8+nth] = __builtin_amdgcn_mfma_f32_16x16x32_bf16(qf[0][dk], kb, acc[0][kh*8+nth], 0, 0, 0);
        acc[1][kh*8+nth] = __builtin_amdgcn_mfma_f32_16x16x32_bf16(qf[1][dk], kb, acc[1][kh*8+nth], 0, 0, 0);
      }
    }
  }

  // ---- mask + softmax (rows live across 16 lanes of a g-group) + P -> LDS ----
  unsigned anybits = 0u;
  unsigned short* Pw = ldsP + wave * 8192;
  #pragma unroll
  for(int mt = 0; mt < 2; ++mt){
    #pragma unroll
    for(int r = 0; r < 4; ++r){
      const int qw = mt*16 + g*4 + r;          // row within wave's 32 (C/D layout row)
      const int ql = wave*32 + qw;
      unsigned w[8];
      #pragma unroll
      for(int j = 0; j < 8; ++j) w[j] = audL[ql*8 + j];
      const unsigned anyw = w[0]|w[1]|w[2]|w[3]|w[4]|w[5]|w[6]|w[7];
      anybits |= (anyw ? 1u : 0u) << (mt*4 + r);
      float m = -3.0e38f;
      #pragma unroll
      for(int nt = 0; nt < 16; ++nt){
        const unsigned bit = (w[nt >> 1] >> (((nt & 1) << 4) + u)) & 1u;
        float s = acc[mt][nt][r] * 0.0625f + (bit ? 0.0f : NEGV);   // /sqrt(256) + mask bias
        acc[mt][nt][r] = s;
        m = fmaxf(m, s);
      }
      #pragma unroll
      for(int d = 1; d < 16; d <<= 1) m = fmaxf(m, __shfl_xor(m, d));
      float ssum = 0.0f;
      #pragma unroll
      for(int nt = 0; nt < 16; ++nt){
        const float p = __expf(acc[mt][nt][r] - m);
        acc[mt][nt][r] = p;
        ssum += p;
      }
      #pragma unroll
      for(int d = 1; d < 16; d <<= 1) ssum += __shfl_xor(ssum, d);
      const float inv = 1.0f / ssum;           // ssum >= 1 always (max element)
      const int swp = (qw & 7) << 3;
      #pragma unroll
      for(int nt = 0; nt < 16; ++nt)
        Pw[qw*256 + ((nt*16 + u) ^ swp)] = f2bf(acc[mt][nt][r] * inv);
    }
  }

  // P A-fragments from own wave's LDS region (D-layout -> A-layout relayout)
  short8 pa[2][8];
  #pragma unroll
  for(int mt = 0; mt < 2; ++mt){
    const int qw = mt*16 + u;
    const unsigned short* pr = Pw + qw*256;
    const int swp = (qw & 7) << 3;
    #pragma unroll
    for(int kt = 0; kt < 8; ++kt)
      pa[mt][kt] = *(const short8*)(pr + ((kt*32 + g*8) ^ swp));
  }

  // ---- x = P V over two staged Vt (rows=d) halves ----
  #pragma unroll
  for(int dh = 0; dh < 2; ++dh){
    __syncthreads();                           // all waves past QK/softmax before KV reuse
    const unsigned short* Vsrc = Vt + (ebase + (size_t)dh * 128) * 256;
    #pragma unroll
    for(int i = 0; i < 16; ++i){
      const int c = tid + i*256;
      const int row = c >> 5, col = (c & 31) * 8;
      short8 d = *(const short8*)(Vsrc + (size_t)row * 256 + col);
      *(short8*)(ldsKV + row*256 + (col ^ ((row & 7) << 3))) = d;
    }
    __syncthreads();
    f32x4 xacc[2][8];
    #pragma unroll
    for(int mt = 0; mt < 2; ++mt)
      #pragma unroll
      for(int dt = 0; dt < 8; ++dt) xacc[mt][dt] = zero4;
    #pragma unroll
    for(int dt = 0; dt < 8; ++dt){
      const unsigned short* vr = ldsKV + (dt*16 + u) * 256;
      const int swv = (u & 7) << 3;
      #pragma unroll
      for(int kt = 0; kt < 8; ++kt){
        short8 bv = *(const short8*)(vr + ((kt*32 + g*8) ^ swv));
        xacc[0][dt] = __builtin_amdgcn_mfma_f32_16x16x32_bf16(pa[0][kt], bv, xacc[0][dt], 0, 0, 0);
        xacc[1][dt] = __builtin_amdgcn_mfma_f32_16x16x32_bf16(pa[1][kt], bv, xacc[1][dt], 0, 0, 0);
      }
    }
    #pragma unroll
    for(int mt = 0; mt < 2; ++mt){
      #pragma unroll
      for(int r = 0; r < 4; ++r){
        const float zf = ((anybits >> (mt*4 + r)) & 1u) ? 1.0f : 0.0f;
        float* orow = out + (ebase + q0 + mt*16 + g*4 + r) * 256 + dh*128;
        #pragma unroll
        for(int dt = 0; dt < 8; ++dt)
          orow[dt*16 + u] = xacc[mt][dt][r] * zf;   // rows with no audible key -> 0
      }
    }
  }
}

extern "C" void kernel_launch(void* const* d_in, const int* in_sizes, int n_in,
                              void* d_out, int out_size, void* d_ws, size_t ws_size,
                              hipStream_t stream){
  (void)in_sizes; (void)n_in; (void)out_size;
  const float* qkv   = (const float*)d_in[0];
  const void*  mask  = d_in[1];
  const float* pos   = (const float*)d_in[2];
  const float* noise = (const float*)d_in[3];
  const float* sp    = (const float*)d_in[4];

  unsigned char* ws = (unsigned char*)d_ws;
  unsigned short* Qb = (unsigned short*)(ws);
  unsigned short* Kb = (unsigned short*)(ws + 16777216);
  unsigned short* Vt = (unsigned short*)(ws + 33554432);
  unsigned*       ad = (unsigned*)(ws + 50331648);
  unsigned*       fl = (unsigned*)(ws + 51380224);
  float* outp = (float*)d_out;
  (void)ws_size;   // requires ~51.4 MB of workspace

  k_detect <<<1,    64,  0, stream>>>((const unsigned*)mask, fl);
  k_prep_qk<<<2048, 256, 0, stream>>>(qkv, noise, sp, Qb, Kb);
  k_prep_vt<<<2048, 256, 0, stream>>>(qkv, noise, Vt);
  k_audible<<<128,  256, 0, stream>>>((const unsigned char*)mask, (const int*)mask, pos, fl, ad);

  hipFuncSetAttribute((const void*)k_attn, hipFuncAttributeMaxDynamicSharedMemorySize, 135168);
  k_attn<<<256, 256, 135168, stream>>>(Qb, Kb, Vt, ad, outp);
}

// Round 2
// 90.795 us; speedup vs baseline: 1.5897x; 1.5897x over previous
//
#include <hip/hip_runtime.h>
#include <hip/hip_bf16.h>
#include <stdint.h>

// TarMAC ensemble attention, MI355X/gfx950.
// E=128 ensembles x NB=256 agents, DQ=DK=DV=256 (D=768), f32 in/out, bf16 MFMA compute.
//
// Pipeline: detect-mask-dtype -> prep Q/K bf16 -> prep V^T bf16 (tiled transpose)
//           -> audible bitmask -> fused attention (QK^T, masked softmax, PV).
// R2: k_audible rewritten — was 74.6us (52% of total) at 5% occupancy / 128 blocks
//     with serial scalar mask loads. Now 1024 blocks, one output word per thread,
//     int4-vectorized mask reads, LDS-staged positions. Same bit math.
//
// Workspace layout (needs ~51.4 MB):
//   Qb  @ 0        : 32768x256 bf16 (16 MiB)   q*(|s|+1), noise[:, :DQ]==0 so skipped
//   Kb  @ 16 MiB   : 32768x256 bf16
//   Vt  @ 32 MiB   : per-e transposed V, rows=d cols=k, bf16
//   aud @ 48 MiB   : 32768 x 8 u32 bit-rows (mask & dist<15)
//   flag@ 49 MiB   : mask dtype flag (1=int32, 0=byte)

#define EE   128
#define NBB  256
#define DDIM 768
#define NEGV (-1000000.0f)

typedef __attribute__((ext_vector_type(8))) short short8;   // 8 x bf16 (4 VGPRs)
typedef __attribute__((ext_vector_type(4))) float f32x4;    // MFMA accumulator

__device__ __forceinline__ unsigned short f2bf(float f){
  union { float f; unsigned u; } v; v.f = f;
  return (unsigned short)((v.u + 0x7FFFu + ((v.u >> 16) & 1u)) >> 16);  // RNE, finite inputs
}

// ---------- kernel 0: mask dtype probe ----------
// bool bytes (90% ones) read as u32 give values like 0x01010101 (>1) => flag 0.
// int32 0/1 values stay <=1 => flag 1.
__global__ void k_detect(const unsigned* __restrict__ mask, unsigned* __restrict__ flag){
  if(threadIdx.x == 0){
    unsigned ok = 1u;
    for(int i = 0; i < 64; ++i) if(mask[i] > 1u){ ok = 0u; break; }
    *flag = ok;
  }
}

// ---------- kernel 1: Q (scaled) and K -> bf16 ----------
__global__ void k_prep_qk(const float* __restrict__ qkv, const float* __restrict__ noise,
                          const float* __restrict__ sp,
                          unsigned short* __restrict__ Qb, unsigned short* __restrict__ Kb){
  const float scale = fabsf(sp[0]) + 1.0f;
  const int total = EE * NBB * 128;            // 4-wide chunks over cols [0,512)
  for(int idx = blockIdx.x * blockDim.x + threadIdx.x; idx < total; idx += gridDim.x * blockDim.x){
    const int n   = idx >> 7;
    const int col = (idx & 127) << 2;          // waves stay uniform across the 256 boundary
    f32x4 v = *(const f32x4*)(qkv + (size_t)n * DDIM + col);
    if(col < 256){                             // Q: noise slice is exactly zero -> skip read
      ushort4 o = make_ushort4(f2bf(v[0]*scale), f2bf(v[1]*scale),
                               f2bf(v[2]*scale), f2bf(v[3]*scale));
      *(ushort4*)(Qb + (size_t)n * 256 + col) = o;
    } else {
      f32x4 nz = *(const f32x4*)(noise + (size_t)n * DDIM + col);
      ushort4 o = make_ushort4(f2bf(v[0]+nz[0]), f2bf(v[1]+nz[1]),
                               f2bf(v[2]+nz[2]), f2bf(v[3]+nz[3]));
      *(ushort4*)(Kb + (size_t)n * 256 + (col - 256)) = o;
    }
  }
}

// ---------- kernel 2: V + noise -> transposed bf16 (Vt[e][d][k]) ----------
__global__ void k_prep_vt(const float* __restrict__ qkv, const float* __restrict__ noise,
                          unsigned short* __restrict__ Vt){
  __shared__ unsigned short tile[64 * 66];     // 64x64 tile, stride 66 to spread banks
  const int b = blockIdx.x;
  const int e = b >> 4, t4 = b & 15;
  const int k0 = (t4 >> 2) << 6, d0 = (t4 & 3) << 6;
  const int u = threadIdx.x & 15, r = threadIdx.x >> 4;
  #pragma unroll
  for(int i = 0; i < 4; ++i){
    const int kl = r + (i << 4);
    const size_t off = ((size_t)(e*NBB + k0 + kl)) * DDIM + 512 + d0 + (u << 2);
    f32x4 v  = *(const f32x4*)(qkv   + off);
    f32x4 nz = *(const f32x4*)(noise + off);
    const int base = kl * 66 + (u << 2);
    tile[base+0] = f2bf(v[0]+nz[0]); tile[base+1] = f2bf(v[1]+nz[1]);
    tile[base+2] = f2bf(v[2]+nz[2]); tile[base+3] = f2bf(v[3]+nz[3]);
  }
  __syncthreads();
  #pragma unroll
  for(int i = 0; i < 4; ++i){
    const int dl = r + (i << 4);
    unsigned short o0 = tile[(u*4+0)*66 + dl];
    unsigned short o1 = tile[(u*4+1)*66 + dl];
    unsigned short o2 = tile[(u*4+2)*66 + dl];
    unsigned short o3 = tile[(u*4+3)*66 + dl];
    *(ushort4*)(Vt + ((size_t)(e*NBB + d0 + dl)) * NBB + k0 + (u << 2)) =
        make_ushort4(o0, o1, o2, o3);
  }
}

// ---------- kernel 3: audible bitmask (mask & dist<15) ----------
// One output u32 word (32 keys) per thread. 1024 blocks x 256 threads.
// Each block's 256 words lie inside ONE ensemble (2048 words/e, 8 blocks/e).
__global__ void k_audible(const unsigned char* __restrict__ m8, const int* __restrict__ m32,
                          const float* __restrict__ pos, const unsigned* __restrict__ flag,
                          unsigned* __restrict__ aud){
  __shared__ float px[NBB], py[NBB];
  const int widx = blockIdx.x * 256 + threadIdx.x;   // global word index [0, 262144)
  const int e = widx >> 11;                          // 2048 words per ensemble
  { // stage this ensemble's 256 agent positions
    const float2 p = *(const float2*)(pos + ((size_t)e * NBB + threadIdx.x) * 2);
    px[threadIdx.x] = p.x; py[threadIdx.x] = p.y;
  }
  __syncthreads();
  const int row = (widx >> 3) & 255;                 // q within ensemble
  const int wj  = widx & 7;                          // which 32-key word
  const int isInt = (*flag != 0u);
  const float qx = px[row], qy = py[row];
  const size_t mbase = ((size_t)(e * NBB + row)) * NBB + wj * 32;
  unsigned w = 0u;
  if(isInt){
    #pragma unroll
    for(int i = 0; i < 8; ++i){
      const int4 mv = *(const int4*)(m32 + mbase + i * 4);
      const int mvals[4] = {mv.x, mv.y, mv.z, mv.w};
      #pragma unroll
      for(int j = 0; j < 4; ++j){
        const int kk = i * 4 + j;
        const int k  = wj * 32 + kk;
        const float dx = px[k] - qx, dy = py[k] - qy;
        // block fp-contract so sqrt boundary matches numpy exactly
        const float d2 = __fadd_rn(__fmul_rn(dx, dx), __fmul_rn(dy, dy));
        if((mvals[j] != 0) && (sqrtf(d2) < 15.0f)) w |= 1u << kk;
      }
    }
  } else {
    #pragma unroll
    for(int i = 0; i < 2; ++i){
      const int4 mv = *(const int4*)(m8 + mbase + i * 16);   // 16 bool bytes
      const int mvals[4] = {mv.x, mv.y, mv.z, mv.w};
      #pragma unroll
      for(int j = 0; j < 4; ++j)
        #pragma unroll
        for(int b = 0; b < 4; ++b){
          const int kk = i * 16 + j * 4 + b;
          const int k  = wj * 32 + kk;
          const float dx = px[k] - qx, dy = py[k] - qy;
          const float d2 = __fadd_rn(__fmul_rn(dx, dx), __fmul_rn(dy, dy));
          if((((unsigned)mvals[j] >> (8 * b)) & 0xFFu) && (sqrtf(d2) < 15.0f)) w |= 1u << kk;
        }
    }
  }
  aud[widx] = w;
}

// ---------- kernel 4: fused attention ----------
// Block = (e, q-half): 4 waves x 32 q-rows. 16x16x32 bf16 MFMA.
// LDS: [0,64K) K/Vt staging halves (swizzled), [64K,128K) per-wave P, [128K,+4K) audible.
__launch_bounds__(256, 1)
__global__ void k_attn(const unsigned short* __restrict__ Qb,
                       const unsigned short* __restrict__ Kb,
                       const unsigned short* __restrict__ Vt,
                       const unsigned* __restrict__ aud,
                       float* __restrict__ out){
  extern __shared__ unsigned char smem[];
  unsigned short* ldsKV = (unsigned short*)smem;
  unsigned short* ldsP  = (unsigned short*)(smem + 65536);
  unsigned*       audL  = (unsigned*)(smem + 131072);

  const int bid   = blockIdx.x;
  const int e     = ((bid & 7) << 4) + (bid >> 4);  // (e,qhalf) pair lands on one XCD
  const int qhalf = (bid >> 3) & 1;
  const int tid   = threadIdx.x;
  const int wave  = tid >> 6;
  const int lane  = tid & 63;
  const int g     = lane >> 4;
  const int u     = lane & 15;
  const int q0    = qhalf * 128 + wave * 32;
  const size_t ebase = (size_t)e * NBB;

  { // stage audible words for this block's 128 rows
    const unsigned* src = aud + (ebase + (size_t)qhalf * 128) * 8;
    #pragma unroll
    for(int i = 0; i < 4; ++i) audL[tid + i*256] = src[tid + i*256];
  }

  // Q A-fragments: Q[q0+mt*16+u][dk*32+g*8 .. +7]
  short8 qf[2][8];
  #pragma unroll
  for(int mt = 0; mt < 2; ++mt)
    #pragma unroll
    for(int dk = 0; dk < 8; ++dk)
      qf[mt][dk] = *(const short8*)(Qb + (ebase + q0 + mt*16 + u) * 256 + dk*32 + g*8);

  const f32x4 zero4 = {0.f, 0.f, 0.f, 0.f};
  f32x4 acc[2][16];
  #pragma unroll
  for(int mt = 0; mt < 2; ++mt)
    #pragma unroll
    for(int nt = 0; nt < 16; ++nt) acc[mt][nt] = zero4;

  // ---- S = Q K^T over two staged K halves ----
  #pragma unroll
  for(int kh = 0; kh < 2; ++kh){
    __syncthreads();
    const unsigned short* Ksrc = Kb + (ebase + (size_t)kh * 128) * 256;
    #pragma unroll
    for(int i = 0; i < 16; ++i){
      const int c = tid + i*256;
      const int row = c >> 5, col = (c & 31) * 8;
      short8 d = *(const short8*)(Ksrc + (size_t)row * 256 + col);
      *(short8*)(ldsKV + row*256 + (col ^ ((row & 7) << 3))) = d;   // XOR bank swizzle
    }
    __syncthreads();
    #pragma unroll
    for(int nth = 0; nth < 8; ++nth){
      const unsigned short* kr = ldsKV + (nth*16 + u) * 256;
      const int sw = (u & 7) << 3;
      #pragma unroll
      for(int dk = 0; dk < 8; ++dk){
        short8 kb = *(const short8*)(kr + ((dk*32 + g*8) ^ sw));
        acc[0][kh*8+nth] = __builtin_amdgcn_mfma_f32_16x16x32_bf16(qf[0][dk], kb, acc[0][kh*8+nth], 0, 0, 0);
        acc[1][kh*8+nth] = __builtin_amdgcn_mfma_f32_16x16x32_bf16(qf[1][dk], kb, acc[1][kh*8+nth], 0, 0, 0);
      }
    }
  }

  // ---- mask + softmax (rows live across 16 lanes of a g-group) + P -> LDS ----
  unsigned anybits = 0u;
  unsigned short* Pw = ldsP + wave * 8192;
  #pragma unroll
  for(int mt = 0; mt < 2; ++mt){
    #pragma unroll
    for(int r = 0; r < 4; ++r){
      const int qw = mt*16 + g*4 + r;          // row within wave's 32 (C/D layout row)
      const int ql = wave*32 + qw;
      unsigned w[8];
      #pragma unroll
      for(int j = 0; j < 8; ++j) w[j] = audL[ql*8 + j];
      const unsigned anyw = w[0]|w[1]|w[2]|w[3]|w[4]|w[5]|w[6]|w[7];
      anybits |= (anyw ? 1u : 0u) << (mt*4 + r);
      float m = -3.0e38f;
      #pragma unroll
      for(int nt = 0; nt < 16; ++nt){
        const unsigned bit = (w[nt >> 1] >> (((nt & 1) << 4) + u)) & 1u;
        float s = acc[mt][nt][r] * 0.0625f + (bit ? 0.0f : NEGV);   // /sqrt(256) + mask bias
        acc[mt][nt][r] = s;
        m = fmaxf(m, s);
      }
      #pragma unroll
      for(int d = 1; d < 16; d <<= 1) m = fmaxf(m, __shfl_xor(m, d));
      float ssum = 0.0f;
      #pragma unroll
      for(int nt = 0; nt < 16; ++nt){
        const float p = __expf(acc[mt][nt][r] - m);
        acc[mt][nt][r] = p;
        ssum += p;
      }
      #pragma unroll
      for(int d = 1; d < 16; d <<= 1) ssum += __shfl_xor(ssum, d);
      const float inv = 1.0f / ssum;           // ssum >= 1 always (max element)
      const int swp = (qw & 7) << 3;
      #pragma unroll
      for(int nt = 0; nt < 16; ++nt)
        Pw[qw*256 + ((nt*16 + u) ^ swp)] = f2bf(acc[mt][nt][r] * inv);
    }
  }

  // P A-fragments from own wave's LDS region (D-layout -> A-layout relayout)
  short8 pa[2][8];
  #pragma unroll
  for(int mt = 0; mt < 2; ++mt){
    const int qw = mt*16 + u;
    const unsigned short* pr = Pw + qw*256;
    const int swp = (qw & 7) << 3;
    #pragma unroll
    for(int kt = 0; kt < 8; ++kt)
      pa[mt][kt] = *(const short8*)(pr + ((kt*32 + g*8) ^ swp));
  }

  // ---- x = P V over two staged Vt (rows=d) halves ----
  #pragma unroll
  for(int dh = 0; dh < 2; ++dh){
    __syncthreads();                           // all waves past QK/softmax before KV reuse
    const unsigned short* Vsrc = Vt + (ebase + (size_t)dh * 128) * 256;
    #pragma unroll
    for(int i = 0; i < 16; ++i){
      const int c = tid + i*256;
      const int row = c >> 5, col = (c & 31) * 8;
      short8 d = *(const short8*)(Vsrc + (size_t)row * 256 + col);
      *(short8*)(ldsKV + row*256 + (col ^ ((row & 7) << 3))) = d;
    }
    __syncthreads();
    f32x4 xacc[2][8];
    #pragma unroll
    for(int mt = 0; mt < 2; ++mt)
      #pragma unroll
      for(int dt = 0; dt < 8; ++dt) xacc[mt][dt] = zero4;
    #pragma unroll
    for(int dt = 0; dt < 8; ++dt){
      const unsigned short* vr = ldsKV + (dt*16 + u) * 256;
      const int swv = (u & 7) << 3;
      #pragma unroll
      for(int kt = 0; kt < 8; ++kt){
        short8 bv = *(const short8*)(vr + ((kt*32 + g*8) ^ swv));
        xacc[0][dt] = __builtin_amdgcn_mfma_f32_16x16x32_bf16(pa[0][kt], bv, xacc[0][dt], 0, 0, 0);
        xacc[1][dt] = __builtin_amdgcn_mfma_f32_16x16x32_bf16(pa[1][kt], bv, xacc[1][dt], 0, 0, 0);
      }
    }
    #pragma unroll
    for(int mt = 0; mt < 2; ++mt){
      #pragma unroll
      for(int r = 0; r < 4; ++r){
        const float zf = ((anybits >> (mt*4 + r)) & 1u) ? 1.0f : 0.0f;
        float* orow = out + (ebase + q0 + mt*16 + g*4 + r) * 256 + dh*128;
        #pragma unroll
        for(int dt = 0; dt < 8; ++dt)
          orow[dt*16 + u] = xacc[mt][dt][r] * zf;   // rows with no audible key -> 0
      }
    }
  }
}

extern "C" void kernel_launch(void* const* d_in, const int* in_sizes, int n_in,
                              void* d_out, int out_size, void* d_ws, size_t ws_size,
                              hipStream_t stream){
  (void)in_sizes; (void)n_in; (void)out_size;
  const float* qkv   = (const float*)d_in[0];
  const void*  mask  = d_in[1];
  const float* pos   = (const float*)d_in[2];
  const float* noise = (const float*)d_in[3];
  const float* sp    = (const float*)d_in[4];

  unsigned char* ws = (unsigned char*)d_ws;
  unsigned short* Qb = (unsigned short*)(ws);
  unsigned short* Kb = (unsigned short*)(ws + 16777216);
  unsigned short* Vt = (unsigned short*)(ws + 33554432);
  unsigned*       ad = (unsigned*)(ws + 50331648);
  unsigned*       fl = (unsigned*)(ws + 51380224);
  float* outp = (float*)d_out;
  (void)ws_size;   // requires ~51.4 MB of workspace

  k_detect <<<1,    64,  0, stream>>>((const unsigned*)mask, fl);
  k_prep_qk<<<2048, 256, 0, stream>>>(qkv, noise, sp, Qb, Kb);
  k_prep_vt<<<2048, 256, 0, stream>>>(qkv, noise, Vt);
  k_audible<<<1024, 256, 0, stream>>>((const unsigned char*)mask, (const int*)mask, pos, fl, ad);

  hipFuncSetAttribute((const void*)k_attn, hipFuncAttributeMaxDynamicSharedMemorySize, 135168);
  k_attn<<<256, 256, 135168, stream>>>(Qb, Kb, Vt, ad, outp);
}

// Round 3
// 77.660 us; speedup vs baseline: 1.8586x; 1.1691x over previous
//
#include <hip/hip_runtime.h>
#include <hip/hip_bf16.h>
#include <stdint.h>

// TarMAC ensemble attention, MI355X/gfx950.
// E=128 ensembles x NB=256 agents, DQ=DK=DV=256 (D=768), f32 in/out, bf16 MFMA compute.
//
// R3: (a) k_attn re-tiled: 512 blocks x 64 q-rows, 66 KB LDS -> 2 independent
//     blocks/CU (was 1 block/CU, 1 wave/SIMD, fully serial phases); staging via
//     global_load_lds dwordx4 with pre-swizzled global source (LDS dest linear).
//     (b) k_detect folded into k_audible (wave __any probe). (c) prep kernels merged.
//
// Workspace layout (needs ~49.4 MB):
//   Qb  @ 0        : 32768x256 bf16 (16 MiB)   q*(|s|+1), noise[:, :DQ]==0 so skipped
//   Kb  @ 16 MiB   : 32768x256 bf16
//   Vt  @ 32 MiB   : per-e transposed V, rows=d cols=k, bf16
//   aud @ 48 MiB   : 32768 x 8 u32 bit-rows (mask & dist<15)

#define EE   128
#define NBB  256
#define DDIM 768
#define NEGV (-1000000.0f)

typedef __attribute__((ext_vector_type(8))) short short8;   // 8 x bf16 (4 VGPRs)
typedef __attribute__((ext_vector_type(4))) float f32x4;    // MFMA accumulator

__device__ __forceinline__ unsigned short f2bf(float f){
  union { float f; unsigned u; } v; v.f = f;
  return (unsigned short)((v.u + 0x7FFFu + ((v.u >> 16) & 1u)) >> 16);  // RNE, finite inputs
}

// async global->LDS, 16B per lane; LDS dest = wave-uniform base + lane*16 (HW rule)
__device__ __forceinline__ void gload16(const void* g, void* l){
  __builtin_amdgcn_global_load_lds((const __attribute__((address_space(1))) unsigned*)g,
                                   (__attribute__((address_space(3))) unsigned*)l, 16, 0, 0);
}

// ---------- kernel 1: fused prep ----------
// blocks [0,2048): Q (scaled) + K -> bf16 rows.  blocks [2048,4096): V -> Vt transpose.
__global__ void k_prep(const float* __restrict__ qkv, const float* __restrict__ noise,
                       const float* __restrict__ sp,
                       unsigned short* __restrict__ Qb, unsigned short* __restrict__ Kb,
                       unsigned short* __restrict__ Vt){
  __shared__ unsigned short tile[64 * 66];
  if(blockIdx.x < 2048){
    const float scale = fabsf(sp[0]) + 1.0f;
    const int total = EE * NBB * 128;            // 4-wide chunks over cols [0,512)
    const int stride = 2048 * 256;
    for(int idx = blockIdx.x * 256 + threadIdx.x; idx < total; idx += stride){
      const int n   = idx >> 7;
      const int col = (idx & 127) << 2;          // waves stay uniform across the 256 boundary
      f32x4 v = *(const f32x4*)(qkv + (size_t)n * DDIM + col);
      if(col < 256){                             // Q: noise slice is exactly zero -> skip read
        ushort4 o = make_ushort4(f2bf(v[0]*scale), f2bf(v[1]*scale),
                                 f2bf(v[2]*scale), f2bf(v[3]*scale));
        *(ushort4*)(Qb + (size_t)n * 256 + col) = o;
      } else {
        f32x4 nz = *(const f32x4*)(noise + (size_t)n * DDIM + col);
        ushort4 o = make_ushort4(f2bf(v[0]+nz[0]), f2bf(v[1]+nz[1]),
                                 f2bf(v[2]+nz[2]), f2bf(v[3]+nz[3]));
        *(ushort4*)(Kb + (size_t)n * 256 + (col - 256)) = o;
      }
    }
  } else {
    const int b = blockIdx.x - 2048;
    const int e = b >> 4, t4 = b & 15;
    const int k0 = (t4 >> 2) << 6, d0 = (t4 & 3) << 6;
    const int u = threadIdx.x & 15, r = threadIdx.x >> 4;
    #pragma unroll
    for(int i = 0; i < 4; ++i){
      const int kl = r + (i << 4);
      const size_t off = ((size_t)(e*NBB + k0 + kl)) * DDIM + 512 + d0 + (u << 2);
      f32x4 v  = *(const f32x4*)(qkv   + off);
      f32x4 nz = *(const f32x4*)(noise + off);
      const int base = kl * 66 + (u << 2);
      tile[base+0] = f2bf(v[0]+nz[0]); tile[base+1] = f2bf(v[1]+nz[1]);
      tile[base+2] = f2bf(v[2]+nz[2]); tile[base+3] = f2bf(v[3]+nz[3]);
    }
    __syncthreads();
    #pragma unroll
    for(int i = 0; i < 4; ++i){
      const int dl = r + (i << 4);
      unsigned short o0 = tile[(u*4+0)*66 + dl];
      unsigned short o1 = tile[(u*4+1)*66 + dl];
      unsigned short o2 = tile[(u*4+2)*66 + dl];
      unsigned short o3 = tile[(u*4+3)*66 + dl];
      *(ushort4*)(Vt + ((size_t)(e*NBB + d0 + dl)) * NBB + k0 + (u << 2)) =
          make_ushort4(o0, o1, o2, o3);
    }
  }
}

// ---------- kernel 2: audible bitmask (mask & dist<15), dtype probe inline ----------
// One output u32 word (32 keys) per thread. 1024 blocks x 256 threads.
__global__ void k_audible(const unsigned char* __restrict__ m8, const int* __restrict__ m32,
                          const float* __restrict__ pos, unsigned* __restrict__ aud){
  __shared__ float px[NBB], py[NBB];
  const int widx = blockIdx.x * 256 + threadIdx.x;   // global word index [0, 262144)
  const int e = widx >> 11;                          // 2048 words per ensemble
  { // stage this ensemble's 256 agent positions
    const float2 p = *(const float2*)(pos + ((size_t)e * NBB + threadIdx.x) * 2);
    px[threadIdx.x] = p.x; py[threadIdx.x] = p.y;
  }
  // dtype probe: int32 0/1 words are always <=1; bool bytes pack to e.g. 0x01010101.
  const unsigned probe = ((const unsigned*)m32)[threadIdx.x & 63];
  const int isInt = !__any(probe > 1u);              // wave-uniform
  __syncthreads();
  const int row = (widx >> 3) & 255;                 // q within ensemble
  const int wj  = widx & 7;                          // which 32-key word
  const float qx = px[row], qy = py[row];
  const size_t mbase = ((size_t)(e * NBB + row)) * NBB + wj * 32;
  unsigned w = 0u;
  if(isInt){
    #pragma unroll
    for(int i = 0; i < 8; ++i){
      const int4 mv = *(const int4*)(m32 + mbase + i * 4);
      const int mvals[4] = {mv.x, mv.y, mv.z, mv.w};
      #pragma unroll
      for(int j = 0; j < 4; ++j){
        const int kk = i * 4 + j;
        const int k  = wj * 32 + kk;
        const float dx = px[k] - qx, dy = py[k] - qy;
        // block fp-contract so sqrt boundary matches numpy exactly
        const float d2 = __fadd_rn(__fmul_rn(dx, dx), __fmul_rn(dy, dy));
        if((mvals[j] != 0) && (sqrtf(d2) < 15.0f)) w |= 1u << kk;
      }
    }
  } else {
    #pragma unroll
    for(int i = 0; i < 2; ++i){
      const int4 mv = *(const int4*)(m8 + mbase + i * 16);   // 16 bool bytes
      const int mvals[4] = {mv.x, mv.y, mv.z, mv.w};
      #pragma unroll
      for(int j = 0; j < 4; ++j)
        #pragma unroll
        for(int b = 0; b < 4; ++b){
          const int kk = i * 16 + j * 4 + b;
          const int k  = wj * 32 + kk;
          const float dx = px[k] - qx, dy = py[k] - qy;
          const float d2 = __fadd_rn(__fmul_rn(dx, dx), __fmul_rn(dy, dy));
          if((((unsigned)mvals[j] >> (8 * b)) & 0xFFu) && (sqrtf(d2) < 15.0f)) w |= 1u << kk;
        }
    }
  }
  aud[widx] = w;
}

// ---------- kernel 3: fused attention ----------
// Block = (e, q-quarter): 4 waves x 16 q-rows each. 16x16x32 bf16 MFMA.
// LDS 66 KB: [0,32K) K/Vt stage quarter (64 rows, read-XOR-swizzled),
//            [32K,64K) per-wave P, [64K,+2K) audible words. -> 2 blocks/CU.
__launch_bounds__(256, 2)
__global__ void k_attn(const unsigned short* __restrict__ Qb,
                       const unsigned short* __restrict__ Kb,
                       const unsigned short* __restrict__ Vt,
                       const unsigned* __restrict__ aud,
                       float* __restrict__ out){
  extern __shared__ unsigned char smem[];
  unsigned short* ldsKV = (unsigned short*)smem;            // 64 x 256 bf16
  unsigned short* ldsP  = (unsigned short*)(smem + 32768);  // 4 waves x 16 x 256 bf16
  unsigned*       audL  = (unsigned*)(smem + 65536);        // 64 x 8 words

  // bid = x + 8*qq + 32*c ; e = 16x + c  -> the 4 q-quarters of an ensemble all
  // land on XCD x (bid%8) and launch within 24 bids of each other -> K/V L2 hits.
  const int bid = blockIdx.x;
  const int e   = ((bid & 7) << 4) + (bid >> 5);
  const int qq  = (bid >> 3) & 3;
  const int tid  = threadIdx.x;
  const int wave = tid >> 6;
  const int lane = tid & 63;
  const int g    = lane >> 4;
  const int u    = lane & 15;
  const int q0   = qq * 64 + wave * 16;        // first q-row of this wave
  const size_t ebase = (size_t)e * NBB;

  { // stage audible words for this block's 64 rows (512 words)
    const unsigned* src = aud + (ebase + (size_t)qq * 64) * 8;
    audL[tid]       = src[tid];
    audL[tid + 256] = src[tid + 256];
  }

  // Q A-fragments: Q[q0+u][dk*32+g*8 .. +7]
  short8 qf[8];
  #pragma unroll
  for(int dk = 0; dk < 8; ++dk)
    qf[dk] = *(const short8*)(Qb + (ebase + q0 + u) * 256 + dk*32 + g*8);

  const f32x4 zero4 = {0.f, 0.f, 0.f, 0.f};
  f32x4 acc[16];
  #pragma unroll
  for(int nt = 0; nt < 16; ++nt) acc[nt] = zero4;

  // ---- S = Q K^T over four staged 64-row K quarters ----
  #pragma unroll
  for(int kq = 0; kq < 4; ++kq){
    __syncthreads();
    { // wave stages rows [wave*16, wave*16+16): 8x global_load_lds dwordx4.
      // LDS linear; XOR swizzle folded into the per-lane GLOBAL column.
      const unsigned short* base = Kb + (ebase + (size_t)kq * 64) * 256;
      #pragma unroll
      for(int i = 0; i < 8; ++i){
        const int lrow = wave*16 + i*2 + (lane >> 5);
        const int col  = ((lane & 31) * 8) ^ ((lrow & 7) << 3);
        gload16(base + (size_t)lrow * 256 + col, ldsKV + (wave*16 + i*2) * 256);
      }
    }
    __syncthreads();
    #pragma unroll
    for(int nth = 0; nth < 4; ++nth){
      const unsigned short* kr = ldsKV + (nth*16 + u) * 256;
      const int sw = (u & 7) << 3;
      #pragma unroll
      for(int dk = 0; dk < 8; ++dk){
        short8 kb = *(const short8*)(kr + ((dk*32 + g*8) ^ sw));
        acc[kq*4 + nth] = __builtin_amdgcn_mfma_f32_16x16x32_bf16(qf[dk], kb, acc[kq*4 + nth], 0, 0, 0);
      }
    }
  }

  // ---- mask + softmax (row lives across the 16 lanes of a g-group) + P -> LDS ----
  unsigned anybits = 0u;
  unsigned short* Pw = ldsP + wave * 4096;
  #pragma unroll
  for(int r = 0; r < 4; ++r){
    const int qw = g*4 + r;                    // row within wave's 16 (C/D layout row)
    unsigned w[8];
    #pragma unroll
    for(int j = 0; j < 8; ++j) w[j] = audL[(wave*16 + qw)*8 + j];
    const unsigned anyw = w[0]|w[1]|w[2]|w[3]|w[4]|w[5]|w[6]|w[7];
    anybits |= (anyw ? 1u : 0u) << r;
    float m = -3.0e38f;
    #pragma unroll
    for(int nt = 0; nt < 16; ++nt){
      const unsigned bit = (w[nt >> 1] >> (((nt & 1) << 4) + u)) & 1u;
      float s = acc[nt][r] * 0.0625f + (bit ? 0.0f : NEGV);   // /sqrt(256) + mask bias
      acc[nt][r] = s;
      m = fmaxf(m, s);
    }
    #pragma unroll
    for(int d = 1; d < 16; d <<= 1) m = fmaxf(m, __shfl_xor(m, d));
    float ssum = 0.0f;
    #pragma unroll
    for(int nt = 0; nt < 16; ++nt){
      const float p = __expf(acc[nt][r] - m);
      acc[nt][r] = p;
      ssum += p;
    }
    #pragma unroll
    for(int d = 1; d < 16; d <<= 1) ssum += __shfl_xor(ssum, d);
    const float inv = 1.0f / ssum;             // ssum >= 1 always (max element)
    const int swp = (qw & 7) << 3;
    #pragma unroll
    for(int nt = 0; nt < 16; ++nt)
      Pw[qw*256 + ((nt*16 + u) ^ swp)] = f2bf(acc[nt][r] * inv);
  }

  // P A-fragments from own wave's LDS region (D-layout -> A-layout relayout)
  short8 pa[8];
  {
    const unsigned short* pr = Pw + u*256;
    const int swp = (u & 7) << 3;
    #pragma unroll
    for(int kt = 0; kt < 8; ++kt)
      pa[kt] = *(const short8*)(pr + ((kt*32 + g*8) ^ swp));
  }

  // ---- x = P V over four staged 64-row Vt quarters (rows = d) ----
  #pragma unroll
  for(int dqt = 0; dqt < 4; ++dqt){
    __syncthreads();                           // all waves done reading ldsKV
    {
      const unsigned short* base = Vt + (ebase + (size_t)dqt * 64) * 256;
      #pragma unroll
      for(int i = 0; i < 8; ++i){
        const int lrow = wave*16 + i*2 + (lane >> 5);
        const int col  = ((lane & 31) * 8) ^ ((lrow & 7) << 3);
        gload16(base + (size_t)lrow * 256 + col, ldsKV + (wave*16 + i*2) * 256);
      }
    }
    __syncthreads();
    f32x4 xacc[4];
    #pragma unroll
    for(int dt = 0; dt < 4; ++dt) xacc[dt] = zero4;
    #pragma unroll
    for(int dt = 0; dt < 4; ++dt){
      const unsigned short* vr = ldsKV + (dt*16 + u) * 256;
      const int sw = (u & 7) << 3;
      #pragma unroll
      for(int kt = 0; kt < 8; ++kt){
        short8 bv = *(const short8*)(vr + ((kt*32 + g*8) ^ sw));
        xacc[dt] = __builtin_amdgcn_mfma_f32_16x16x32_bf16(pa[kt], bv, xacc[dt], 0, 0, 0);
      }
    }
    #pragma unroll
    for(int r = 0; r < 4; ++r){
      const float zf = ((anybits >> r) & 1u) ? 1.0f : 0.0f;
      float* orow = out + (ebase + q0 + g*4 + r) * 256 + dqt*64;
      #pragma unroll
      for(int dt = 0; dt < 4; ++dt)
        orow[dt*16 + u] = xacc[dt][r] * zf;    // rows with no audible key -> 0
    }
  }
}

extern "C" void kernel_launch(void* const* d_in, const int* in_sizes, int n_in,
                              void* d_out, int out_size, void* d_ws, size_t ws_size,
                              hipStream_t stream){
  (void)in_sizes; (void)n_in; (void)out_size;
  const float* qkv   = (const float*)d_in[0];
  const void*  mask  = d_in[1];
  const float* pos   = (const float*)d_in[2];
  const float* noise = (const float*)d_in[3];
  const float* sp    = (const float*)d_in[4];

  unsigned char* ws = (unsigned char*)d_ws;
  unsigned short* Qb = (unsigned short*)(ws);
  unsigned short* Kb = (unsigned short*)(ws + 16777216);
  unsigned short* Vt = (unsigned short*)(ws + 33554432);
  unsigned*       ad = (unsigned*)(ws + 50331648);
  float* outp = (float*)d_out;
  (void)ws_size;   // requires ~49.4 MB of workspace

  k_prep   <<<4096, 256, 0, stream>>>(qkv, noise, sp, Qb, Kb, Vt);
  k_audible<<<1024, 256, 0, stream>>>((const unsigned char*)mask, (const int*)mask, pos, ad);

  hipFuncSetAttribute((const void*)k_attn, hipFuncAttributeMaxDynamicSharedMemorySize, 67584);
  k_attn<<<512, 256, 67584, stream>>>(Qb, Kb, Vt, ad, outp);
}

// Round 4
// 66.904 us; speedup vs baseline: 2.1574x; 1.1608x over previous
//
#include <hip/hip_runtime.h>
#include <hip/hip_bf16.h>
#include <stdint.h>

// TarMAC ensemble attention, MI355X/gfx950.
// E=128 ensembles x NB=256 agents, DQ=DK=DV=256 (D=768), f32 in/out, bf16 MFMA compute.
//
// R4: Q/K bf16 prep + audible mask FUSED into k_attn (the Qb/Kb workspace pass was a
//     pure cast round-trip: 134 MB read + 33 MB write + 33 MB read-back). k_prep now
//     only builds Vt (transposed V bf16). K f32 re-read x4 per ensemble stays in L2
//     (same-XCD block swizzle). Vt quarter-0 gload hoisted above softmax (latency hide).
//
// Workspace: Vt @ 0 : per-e transposed V, rows=d cols=k, bf16 (16 MiB).

#define EE   128
#define NBB  256
#define DDIM 768
#define NEGV (-1000000.0f)

typedef __attribute__((ext_vector_type(8))) short short8;   // 8 x bf16 (4 VGPRs)
typedef __attribute__((ext_vector_type(4))) float f32x4;    // MFMA accumulator

__device__ __forceinline__ unsigned short f2bf(float f){
  union { float f; unsigned u; } v; v.f = f;
  return (unsigned short)((v.u + 0x7FFFu + ((v.u >> 16) & 1u)) >> 16);  // RNE, finite inputs
}
// RNE cast the compiler can fuse into v_cvt_pk_bf16_f32 (m240: don't hand-write asm)
__device__ __forceinline__ unsigned short cvt1(float f){
  __hip_bfloat16 h = __float2bfloat16(f);
  unsigned short u; __builtin_memcpy(&u, &h, 2); return u;
}

// async global->LDS, 16B per lane; LDS dest = wave-uniform base + lane*16 (HW rule)
__device__ __forceinline__ void gload16(const void* g, void* l){
  __builtin_amdgcn_global_load_lds((const __attribute__((address_space(1))) unsigned*)g,
                                   (__attribute__((address_space(3))) unsigned*)l, 16, 0, 0);
}

// ---------- kernel 1: V + noise -> transposed bf16 (Vt[e][d][k]) ----------
__global__ void k_prep_vt(const float* __restrict__ qkv, const float* __restrict__ noise,
                          unsigned short* __restrict__ Vt){
  __shared__ unsigned short tile[64 * 66];     // 64x64 tile, stride 66 to spread banks
  const int b = blockIdx.x;
  const int e = b >> 4, t4 = b & 15;
  const int k0 = (t4 >> 2) << 6, d0 = (t4 & 3) << 6;
  const int u = threadIdx.x & 15, r = threadIdx.x >> 4;
  #pragma unroll
  for(int i = 0; i < 4; ++i){
    const int kl = r + (i << 4);
    const size_t off = ((size_t)(e*NBB + k0 + kl)) * DDIM + 512 + d0 + (u << 2);
    f32x4 v  = *(const f32x4*)(qkv   + off);
    f32x4 nz = *(const f32x4*)(noise + off);
    const int base = kl * 66 + (u << 2);
    tile[base+0] = f2bf(v[0]+nz[0]); tile[base+1] = f2bf(v[1]+nz[1]);
    tile[base+2] = f2bf(v[2]+nz[2]); tile[base+3] = f2bf(v[3]+nz[3]);
  }
  __syncthreads();
  #pragma unroll
  for(int i = 0; i < 4; ++i){
    const int dl = r + (i << 4);
    unsigned short o0 = tile[(u*4+0)*66 + dl];
    unsigned short o1 = tile[(u*4+1)*66 + dl];
    unsigned short o2 = tile[(u*4+2)*66 + dl];
    unsigned short o3 = tile[(u*4+3)*66 + dl];
    *(ushort4*)(Vt + ((size_t)(e*NBB + d0 + dl)) * NBB + k0 + (u << 2)) =
        make_ushort4(o0, o1, o2, o3);
  }
}

// ---------- kernel 2: fused attention (aud + Q/K convert + QK^T + softmax + PV) ----
// Block = (e, q-quarter): 4 waves x 16 q-rows each. 16x16x32 bf16 MFMA.
// LDS 68 KB: [0,32K) K/Vt stage quarter (64 rows, read-XOR-swizzled),
//            [32K,64K) per-wave P, [64K,+2K) aud words, [66K,+2K) positions.
// 2 blocks/CU; the 4 quarters of an ensemble share one XCD's L2 (K f32 + Vt reuse).
__launch_bounds__(256, 2)
__global__ void k_attn(const float* __restrict__ qkv, const float* __restrict__ noise,
                       const float* __restrict__ sp,
                       const unsigned char* __restrict__ m8, const int* __restrict__ m32,
                       const float* __restrict__ pos,
                       const unsigned short* __restrict__ Vt,
                       float* __restrict__ out){
  extern __shared__ unsigned char smem[];
  unsigned short* ldsKV = (unsigned short*)smem;            // 64 x 256 bf16
  unsigned short* ldsP  = (unsigned short*)(smem + 32768);  // 4 waves x 16 x 256 bf16
  unsigned*       audL  = (unsigned*)(smem + 65536);        // 64 rows x 8 words
  float*          posx  = (float*)(smem + 67584);           // 256
  float*          posy  = (float*)(smem + 68608);           // 256

  // bid = x + 8*qq + 32*c ; e = 16x + c  -> the 4 q-quarters of an ensemble all
  // land on XCD x (bid%8) and launch within 24 bids of each other -> L2 reuse.
  const int bid = blockIdx.x;
  const int e   = ((bid & 7) << 4) + (bid >> 5);
  const int qq  = (bid >> 3) & 3;
  const int tid  = threadIdx.x;
  const int wave = tid >> 6;
  const int lane = tid & 63;
  const int g    = lane >> 4;
  const int u    = lane & 15;
  const int q0   = qq * 64 + wave * 16;        // first q-row of this wave
  const size_t ebase = (size_t)e * NBB;

  // ---- phase 0: positions + audible bitmask (fused k_audible, identical math) ----
  {
    const float2 p = *(const float2*)(pos + (ebase + tid) * 2);
    posx[tid] = p.x; posy[tid] = p.y;
  }
  // dtype probe: int32 0/1 words are always <=1; bool bytes pack to e.g. 0x01010101.
  const unsigned probe = ((const unsigned*)m32)[tid & 63];
  const int isInt = !__any(probe > 1u);        // wave-uniform
  __syncthreads();
  #pragma unroll
  for(int h = 0; h < 2; ++h){
    const int w   = tid + h * 256;             // word index within block [0,512)
    const int row = w >> 3;                    // q-row within block [0,64)
    const int j   = w & 7;                     // which 32-key word
    const float qx = posx[qq*64 + row], qy = posy[qq*64 + row];
    const size_t mbase = (ebase + qq*64 + row) * NBB + j * 32;
    unsigned wd = 0u;
    if(isInt){
      #pragma unroll
      for(int i = 0; i < 8; ++i){
        const int4 mv = *(const int4*)(m32 + mbase + i * 4);
        const int mvals[4] = {mv.x, mv.y, mv.z, mv.w};
        #pragma unroll
        for(int jj = 0; jj < 4; ++jj){
          const int kk = i * 4 + jj;
          const int k  = j * 32 + kk;
          const float dx = posx[k] - qx, dy = posy[k] - qy;
          // block fp-contract so sqrt boundary matches numpy exactly
          const float d2 = __fadd_rn(__fmul_rn(dx, dx), __fmul_rn(dy, dy));
          if((mvals[jj] != 0) && (sqrtf(d2) < 15.0f)) wd |= 1u << kk;
        }
      }
    } else {
      #pragma unroll
      for(int i = 0; i < 2; ++i){
        const int4 mv = *(const int4*)(m8 + mbase + i * 16);   // 16 bool bytes
        const int mvals[4] = {mv.x, mv.y, mv.z, mv.w};
        #pragma unroll
        for(int jj = 0; jj < 4; ++jj)
          #pragma unroll
          for(int b = 0; b < 4; ++b){
            const int kk = i * 16 + jj * 4 + b;
            const int k  = j * 32 + kk;
            const float dx = posx[k] - qx, dy = posy[k] - qy;
            const float d2 = __fadd_rn(__fmul_rn(dx, dx), __fmul_rn(dy, dy));
            if((((unsigned)mvals[jj] >> (8 * b)) & 0xFFu) && (sqrtf(d2) < 15.0f)) wd |= 1u << kk;
          }
      }
    }
    audL[w] = wd;
  }

  // ---- phase 1: Q A-fragments straight from f32 global (scale + RNE cvt) ----
  const float scale = fabsf(sp[0]) + 1.0f;
  short8 qf[8];
  {
    const float* qrow = qkv + (ebase + q0 + u) * DDIM;
    #pragma unroll
    for(int dk = 0; dk < 8; ++dk){
      f32x4 a = *(const f32x4*)(qrow + dk*32 + g*8);
      f32x4 b = *(const f32x4*)(qrow + dk*32 + g*8 + 4);
      short8 f;
      f[0]=cvt1(a[0]*scale); f[1]=cvt1(a[1]*scale); f[2]=cvt1(a[2]*scale); f[3]=cvt1(a[3]*scale);
      f[4]=cvt1(b[0]*scale); f[5]=cvt1(b[1]*scale); f[6]=cvt1(b[2]*scale); f[7]=cvt1(b[3]*scale);
      qf[dk] = f;
    }
  }

  const f32x4 zero4 = {0.f, 0.f, 0.f, 0.f};
  f32x4 acc[16];
  #pragma unroll
  for(int nt = 0; nt < 16; ++nt) acc[nt] = zero4;

  // ---- phase 2: S = Q K^T; K staged f32->bf16 in-block per 64-row quarter ----
  #pragma unroll
  for(int kq = 0; kq < 4; ++kq){
    __syncthreads();
    { // wave stages rows [wave*16, +16): lane = one f32x4 (+noise) per row, coalesced;
      // swizzled ds_write_b64 (2 lanes/bank = free).
      #pragma unroll
      for(int i = 0; i < 16; ++i){
        const int row = wave*16 + i;
        const size_t goff = (ebase + kq*64 + row) * DDIM + 256 + lane*4;
        f32x4 a  = *(const f32x4*)(qkv + goff);
        f32x4 nz = *(const f32x4*)(noise + goff);
        uint2 o;
        o.x = (unsigned)cvt1(a[0]+nz[0]) | ((unsigned)cvt1(a[1]+nz[1]) << 16);
        o.y = (unsigned)cvt1(a[2]+nz[2]) | ((unsigned)cvt1(a[3]+nz[3]) << 16);
        const int col = (lane*4) ^ ((row & 7) << 3);
        *(uint2*)(ldsKV + row*256 + col) = o;
      }
    }
    __syncthreads();
    #pragma unroll
    for(int nth = 0; nth < 4; ++nth){
      const unsigned short* kr = ldsKV + (nth*16 + u) * 256;
      const int sw = (u & 7) << 3;
      #pragma unroll
      for(int dk = 0; dk < 8; ++dk){
        short8 kb = *(const short8*)(kr + ((dk*32 + g*8) ^ sw));
        acc[kq*4 + nth] = __builtin_amdgcn_mfma_f32_16x16x32_bf16(qf[dk], kb, acc[kq*4 + nth], 0, 0, 0);
      }
    }
  }

  __syncthreads();                             // all waves done reading ldsKV (K)
  { // hoist Vt quarter-0 gload: its latency hides under the softmax VALU below
    const unsigned short* base = Vt + (ebase + 0) * 256;
    #pragma unroll
    for(int i = 0; i < 8; ++i){
      const int lrow = wave*16 + i*2 + (lane >> 5);
      const int col  = ((lane & 31) * 8) ^ ((lrow & 7) << 3);
      gload16(base + (size_t)lrow * 256 + col, ldsKV + (wave*16 + i*2) * 256);
    }
  }

  // ---- phase 3: mask + softmax (row across 16 lanes of a g-group) + P -> LDS ----
  unsigned anybits = 0u;
  unsigned short* Pw = ldsP + wave * 4096;
  #pragma unroll
  for(int r = 0; r < 4; ++r){
    const int qw = g*4 + r;                    // row within wave's 16 (C/D layout row)
    unsigned w[8];
    #pragma unroll
    for(int j = 0; j < 8; ++j) w[j] = audL[(wave*16 + qw)*8 + j];
    const unsigned anyw = w[0]|w[1]|w[2]|w[3]|w[4]|w[5]|w[6]|w[7];
    anybits |= (anyw ? 1u : 0u) << r;
    float m = -3.0e38f;
    #pragma unroll
    for(int nt = 0; nt < 16; ++nt){
      const unsigned bit = (w[nt >> 1] >> (((nt & 1) << 4) + u)) & 1u;
      float s = acc[nt][r] * 0.0625f + (bit ? 0.0f : NEGV);   // /sqrt(256) + mask bias
      acc[nt][r] = s;
      m = fmaxf(m, s);
    }
    #pragma unroll
    for(int d = 1; d < 16; d <<= 1) m = fmaxf(m, __shfl_xor(m, d));
    float ssum = 0.0f;
    #pragma unroll
    for(int nt = 0; nt < 16; ++nt){
      const float p = __expf(acc[nt][r] - m);
      acc[nt][r] = p;
      ssum += p;
    }
    #pragma unroll
    for(int d = 1; d < 16; d <<= 1) ssum += __shfl_xor(ssum, d);
    const float inv = 1.0f / ssum;             // ssum >= 1 always (max element)
    const int swp = (qw & 7) << 3;
    #pragma unroll
    for(int nt = 0; nt < 16; ++nt)
      Pw[qw*256 + ((nt*16 + u) ^ swp)] = f2bf(acc[nt][r] * inv);
  }

  // P A-fragments from own wave's LDS region (D-layout -> A-layout relayout;
  // same-wave write->read, compiler's lgkmcnt covers it)
  short8 pa[8];
  {
    const unsigned short* pr = Pw + u*256;
    const int swp = (u & 7) << 3;
    #pragma unroll
    for(int kt = 0; kt < 8; ++kt)
      pa[kt] = *(const short8*)(pr + ((kt*32 + g*8) ^ swp));
  }

  // ---- phase 4: x = P V over four staged 64-row Vt quarters (rows = d) ----
  __syncthreads();                             // quarter-0 gload drained (vmcnt0+barrier)
  #pragma unroll
  for(int dqt = 0; dqt < 4; ++dqt){
    f32x4 xacc[4];
    #pragma unroll
    for(int dt = 0; dt < 4; ++dt) xacc[dt] = zero4;
    #pragma unroll
    for(int dt = 0; dt < 4; ++dt){
      const unsigned short* vr = ldsKV + (dt*16 + u) * 256;
      const int sw = (u & 7) << 3;
      #pragma unroll
      for(int kt = 0; kt < 8; ++kt){
        short8 bv = *(const short8*)(vr + ((kt*32 + g*8) ^ sw));
        xacc[dt] = __builtin_amdgcn_mfma_f32_16x16x32_bf16(pa[kt], bv, xacc[dt], 0, 0, 0);
      }
    }
    #pragma unroll
    for(int r = 0; r < 4; ++r){
      const float zf = ((anybits >> r) & 1u) ? 1.0f : 0.0f;
      float* orow = out + (ebase + q0 + g*4 + r) * 256 + dqt*64;
      #pragma unroll
      for(int dt = 0; dt < 4; ++dt)
        orow[dt*16 + u] = xacc[dt][r] * zf;    // rows with no audible key -> 0
    }
    if(dqt < 3){
      __syncthreads();                         // all waves done reading ldsKV
      const unsigned short* base = Vt + (ebase + (size_t)(dqt+1) * 64) * 256;
      #pragma unroll
      for(int i = 0; i < 8; ++i){
        const int lrow = wave*16 + i*2 + (lane >> 5);
        const int col  = ((lane & 31) * 8) ^ ((lrow & 7) << 3);
        gload16(base + (size_t)lrow * 256 + col, ldsKV + (wave*16 + i*2) * 256);
      }
      __syncthreads();
    }
  }
}

extern "C" void kernel_launch(void* const* d_in, const int* in_sizes, int n_in,
                              void* d_out, int out_size, void* d_ws, size_t ws_size,
                              hipStream_t stream){
  (void)in_sizes; (void)n_in; (void)out_size; (void)ws_size;  // needs 16 MB ws
  const float* qkv   = (const float*)d_in[0];
  const void*  mask  = d_in[1];
  const float* pos   = (const float*)d_in[2];
  const float* noise = (const float*)d_in[3];
  const float* sp    = (const float*)d_in[4];

  unsigned short* Vt = (unsigned short*)d_ws;
  float* outp = (float*)d_out;

  k_prep_vt<<<2048, 256, 0, stream>>>(qkv, noise, Vt);

  hipFuncSetAttribute((const void*)k_attn, hipFuncAttributeMaxDynamicSharedMemorySize, 69632);
  k_attn<<<512, 256, 69632, stream>>>(qkv, noise, sp,
                                      (const unsigned char*)mask, (const int*)mask,
                                      pos, Vt, outp);
}